// Round 11
// baseline (80.557 us; speedup 1.0000x reference)
//
#include <hip/hip_runtime.h>

#define N_      4096
#define D_      4096
#define H_      256
#define C_      16
#define NNZ_ATTR 262144
#define E_      131072
#define NNZ_JM  400000
#define NNZ_JA  80000
#define WORDS   128        // N_/32 words per bitmask row
#define ADJ_STRIDE 128     // max neighbors kept per row (deg ~21 avg, max ~45)
#define NT      256
#define MAXCOLS 208        // attr cols per row cap (mean 64, sd 8) + dups

typedef _Float16 half8v __attribute__((ext_vector_type(8)));
typedef _Float16 half2v __attribute__((ext_vector_type(2)));

// ---------------- workspace layout (bytes), ~110 MB of 256 MB ----------------
#define OFF_XSLOT ((size_t)0)                       // 64 MB attr race slots u32 [N][D] (NOT zeroed)
#define OFF_EBB  ((size_t)64<<20)                   // 16 MB edge byte mask [q][p] (zeroed)
#define OFF_XB   (OFF_EBB + ((size_t)16<<20))       // 16 MB attr byte mask [r][c] (zeroed)
#define OFF_ABT  (OFF_XB + ((size_t)16<<20))        // 2 MB a_aug^T bit mask (zeroed)
#define OFF_CNT  (OFF_ABT + ((size_t)2<<20))        // 16 KB dup counters (zeroed)
#define OFF_CCOL (OFF_CNT + ((size_t)16<<10))       // 256 KB dup col slots [N][16]
#define OFF_ADJ  (OFF_CCOL + ((size_t)256<<10))     // 2 MB adjacency lists [N][128]
#define OFF_DINV (OFF_ADJ + ((size_t)2<<20))        // 16 KB
#define OFF_DEG  (OFF_DINV + ((size_t)16<<10))      // 16 KB
#define OFF_W1T  (OFF_DEG + ((size_t)16<<10))       // 2 MB W1^T fp16 [D][H]
#define OFF_H1   (OFF_W1T + ((size_t)2<<20))        // 2 MB h1s fp16 [N][H]
#define OFF_H2   (OFF_H1 + ((size_t)2<<20))         // 256 KB h2s f32

// zero span: ebb+xb+abt+cnt contiguous = 35,667,968 B = 8708 * 256 * 16
#define ZB_BLOCKS  8708
#define XS_BLOCKS  1024    // attr pass A: 262144 stores
#define TR_BLOCKS  1024    // W1 transpose

// k_scat block ranges
#define SC_ATTR  1024      // attr pass B: [0,1024)    262144 exact
#define SC_EDGE  1536      // edges:       [1024,1536) 131072 exact
#define SC_JA    1849      // ja:          [1536,1849) 80000 guarded
#define SC_TOT   1865      // diag:        [1849,1865) 4096 exact

// ---------------- K1: zero masks | attr pass A (race stores) | W1 -> W1T fp16 ----------------
__global__ void k_pre(const float* __restrict__ w1, _Float16* __restrict__ w1t,
                      const int* __restrict__ attr_row, const int* __restrict__ attr_col,
                      unsigned* __restrict__ xslot, uint4* __restrict__ zbase) {
    __shared__ float tile[32][33];
    int b = blockIdx.x, t = threadIdx.x;
    if (b < ZB_BLOCKS) {
        zbase[(size_t)b * NT + t] = make_uint4(0u, 0u, 0u, 0u);
    } else if (b < ZB_BLOCKS + XS_BLOCKS) {
        int i = (b - ZB_BLOCKS) * NT + t;             // 262144 exact
        int r = attr_row[i], c = attr_col[i];
        xslot[(size_t)r * D_ + c] = (unsigned)i;      // last-writer-wins; untouched cells never read
    } else {
        int bb = b - ZB_BLOCKS - XS_BLOCKS;
        int gx = bb & 127, gy = bb >> 7;              // 128 D-tiles, 8 H-tiles
        int tx = t & 31, ty = t >> 5;                 // (32,8)
        int col = gx * 32 + tx;
        #pragma unroll
        for (int j = 0; j < 4; ++j)
            tile[ty + j * 8][tx] = w1[(size_t)(gy * 32 + ty + j * 8) * D_ + col];
        __syncthreads();
        int ocol = gy * 32 + tx;
        #pragma unroll
        for (int j = 0; j < 4; ++j)
            w1t[(size_t)(gx * 32 + ty + j * 8) * H_ + ocol] = (_Float16)tile[tx][ty + j * 8];
    }
}

// ---------------- K2: attr pass B | edges->bytes | ja->abt | diag->abt ----------------
__global__ void k_scat(const int* __restrict__ attr_row, const int* __restrict__ attr_col,
                       const int* __restrict__ edge, const int* __restrict__ jaug,
                       const unsigned* __restrict__ xslot,
                       unsigned char* __restrict__ ebb, unsigned char* __restrict__ xb,
                       unsigned* __restrict__ abt, unsigned* __restrict__ cnt,
                       unsigned* __restrict__ ccol) {
    const int b = blockIdx.x, t = threadIdx.x;
    if (b < SC_ATTR) {                       // attr pass B
        int i = b * NT + t;
        int r = attr_row[i], c = attr_col[i];
        if (xslot[(size_t)r * D_ + c] == (unsigned)i) {
            xb[(size_t)r * D_ + c] = 1;      // winner: plain byte store
        } else {                             // true duplicate occurrence (~2K total)
            unsigned pos = atomicAdd(&cnt[r], 1u);
            if (pos < 16u) ccol[r * 16 + pos] = (unsigned)c;
        }
    } else if (b < SC_EDGE) {                // edges: plain byte store, no RMW
        int j = (b - SC_ATTR) * NT + t;
        int p = edge[j], q = edge[E_ + j];
        ebb[(size_t)q * N_ + p] = 1;
    } else if (b < SC_JA) {                  // ja -> abt bits (80000 guarded)
        int j = (b - SC_EDGE) * NT + t;
        if (j < NNZ_JA) {
            int p = jaug[j], q = jaug[NNZ_JA + j];
            atomicOr(&abt[(size_t)q * WORDS + (p >> 5)], 1u << (p & 31));
        }
    } else {                                 // diag -> abt bits (4096 exact)
        int r = (b - SC_JA) * NT + t;
        atomicOr(&abt[(size_t)r * WORDS + (r >> 5)], 1u << (r & 31));
    }
}

// ---------------- K3: jm entries probe edge bytes; hits -> abt ----------------
__global__ void k_probe(const int* __restrict__ jmsk,
                        const unsigned char* __restrict__ ebb, unsigned* __restrict__ abt) {
    int i = blockIdx.x * NT + threadIdx.x;
    if (i >= NNZ_JM) return;
    int p = jmsk[i], q = jmsk[NNZ_JM + i];
    if (ebb[(size_t)q * N_ + p])
        atomicOr(&abt[(size_t)q * WORDS + (p >> 5)], 1u << (p & 31));
}

// ---------------- K4: abt -> adj/dinv/deg; xb row scan -> col list; h1s fp16 ----------------
__global__ void k_rowh1(const unsigned* __restrict__ abt, const unsigned char* __restrict__ xb,
                        const unsigned* __restrict__ cnt, const unsigned* __restrict__ ccol,
                        const _Float16* __restrict__ w1t,
                        float* __restrict__ dinv, int* __restrict__ deg,
                        int* __restrict__ adj, _Float16* __restrict__ h1s) {
    __shared__ unsigned cols[MAXCOLS];
    __shared__ int lcnt;
    __shared__ float part[4][2][32][8];
    __shared__ float sdinv4[4];
    const int b = blockIdx.x, t = threadIdx.x;
    int wv = t >> 6, lane = t & 63;
    int q = 4 * b + wv;
    {
        uint2 m2 = ((const uint2*)(abt + (size_t)q * WORDS))[lane];
        unsigned w0 = m2.x, w1b = m2.y;
        int c = __popc(w0) + __popc(w1b);
        int pre = c;
        #pragma unroll
        for (int d2 = 1; d2 < 64; d2 <<= 1) {
            int x = __shfl_up(pre, d2);
            if (lane >= d2) pre += x;
        }
        int excl = pre - c;
        int total = __shfl(pre, 63);
        if (lane == 0) {
            float dv = rsqrtf((float)total);
            dinv[q] = dv;
            sdinv4[wv] = dv;
            deg[q] = total < ADJ_STRIDE ? total : ADJ_STRIDE;
        }
        unsigned idx = (unsigned)excl;
        int* arow = adj + (size_t)q * ADJ_STRIDE;
        int base0 = lane * 64;
        while (w0)  { int bp = __ffs(w0) - 1;  w0  &= w0 - 1;  if (idx < ADJ_STRIDE) arow[idx] = base0 + bp;      ++idx; }
        while (w1b) { int bp = __ffs(w1b) - 1; w1b &= w1b - 1; if (idx < ADJ_STRIDE) arow[idx] = base0 + 32 + bp; ++idx; }
    }
    __syncthreads();
    int g = t >> 6, hw = (t >> 5) & 1, l32 = t & 31;
    for (int i = 0; i < 4; ++i) {
        int r = 4 * b + i;
        if (t == 0) lcnt = 0;
        __syncthreads();
        uint4 xv = *(const uint4*)(xb + (size_t)r * D_ + t * 16);
        unsigned wz[4] = {xv.x, xv.y, xv.z, xv.w};
        #pragma unroll
        for (int w4 = 0; w4 < 4; ++w4) {
            unsigned u = wz[w4];
            if (u) {
                #pragma unroll
                for (int bb = 0; bb < 4; ++bb) {
                    if ((u >> (8 * bb)) & 0xffu) {
                        int idx = atomicAdd(&lcnt, 1);
                        if (idx < MAXCOLS) cols[idx] = t * 16 + w4 * 4 + bb;
                    }
                }
            }
        }
        unsigned dn = cnt[r]; if (dn > 16u) dn = 16u;
        if ((unsigned)t < dn) {
            int idx = atomicAdd(&lcnt, 1);
            if (idx < MAXCOLS) cols[idx] = ccol[r * 16 + t];
        }
        __syncthreads();
        int m = lcnt < MAXCOLS ? lcnt : MAXCOLS;
        float acc[8];
        #pragma unroll
        for (int e = 0; e < 8; ++e) acc[e] = 0.f;
        int sub = (g << 1) + hw;
        for (int j = 0; j < m; j += 8) {
            int jc = j + sub;
            if (jc < m) {
                unsigned c = cols[jc];
                half8v v = *(const half8v*)(w1t + (size_t)c * H_ + l32 * 8);
                #pragma unroll
                for (int e = 0; e < 8; ++e) acc[e] += (float)v[e];
            }
        }
        #pragma unroll
        for (int e = 0; e < 8; ++e) part[g][hw][l32][e] = acc[e];
        __syncthreads();
        int l = t >> 3, e = t & 7;
        float s = 0.f;
        #pragma unroll
        for (int gg = 0; gg < 4; ++gg) {
            s += part[gg][0][l][e];
            s += part[gg][1][l][e];
        }
        h1s[(size_t)r * H_ + t] = (_Float16)(s * sdinv4[i]);
        __syncthreads();
    }
}

// ---------------- K5: out1 = relu(dinv*sum_adj h1s); h2s = dinv*(out1 @ W2^T) ----------------
__global__ void k_prop1(const int* __restrict__ adj, const int* __restrict__ deg,
                        const float* __restrict__ dinv, const _Float16* __restrict__ h1s,
                        const float* __restrict__ w2, float* __restrict__ h2s) {
    __shared__ int adj_s[128];
    __shared__ float partial2[2][256];
    __shared__ float hrow[256];
    __shared__ float partial[16][17];
    const int b = blockIdx.x, t = threadIdx.x;
    int g2 = t >> 7, tt = t & 127;
    int c = t & 15, gg = t >> 4;
    float w2r[16];
    #pragma unroll
    for (int kk = 0; kk < 16; ++kk) w2r[kk] = w2[(size_t)c * H_ + gg * 16 + kk];
    for (int i = 0; i < 4; ++i) {
        int q = 4 * b + i;
        __syncthreads();
        if (t < ADJ_STRIDE) adj_s[t] = adj[(size_t)q * ADJ_STRIDE + t];
        __syncthreads();
        int dg = deg[q];
        float ax = 0.f, ay = 0.f;
        int j = g2;
        for (; j + 2 < dg; j += 4) {
            int p0 = adj_s[j], p1 = adj_s[j + 2];
            half2v v0 = *(const half2v*)(h1s + (size_t)p0 * H_ + tt * 2);
            half2v v1 = *(const half2v*)(h1s + (size_t)p1 * H_ + tt * 2);
            ax += (float)v0[0] + (float)v1[0];
            ay += (float)v0[1] + (float)v1[1];
        }
        for (; j < dg; j += 2) {
            int p0 = adj_s[j];
            half2v v0 = *(const half2v*)(h1s + (size_t)p0 * H_ + tt * 2);
            ax += (float)v0[0];
            ay += (float)v0[1];
        }
        partial2[g2][2 * tt]     = ax;
        partial2[g2][2 * tt + 1] = ay;
        __syncthreads();
        float dq = dinv[q];
        hrow[t] = fmaxf((partial2[0][t] + partial2[1][t]) * dq, 0.f);
        __syncthreads();
        float p = 0.f;
        #pragma unroll
        for (int kk = 0; kk < 16; ++kk) p += hrow[gg * 16 + kk] * w2r[kk];
        partial[gg][c] = p;
        __syncthreads();
        if (t < 16) {
            float s = 0.f;
            #pragma unroll
            for (int g3 = 0; g3 < 16; ++g3) s += partial[g3][t];
            h2s[(size_t)q * C_ + t] = s * dq;
        }
    }
}

// ---------------- K6: out[q,c] = dinv[q]*sum_adj h2s[p,c] + bias[c] ----------------
__global__ void k_prop2(const int* __restrict__ adj, const int* __restrict__ deg,
                        const float* __restrict__ dinv, const float* __restrict__ h2s,
                        const float* __restrict__ bias, float* __restrict__ out) {
    const int b = blockIdx.x, t = threadIdx.x;
    int wv = t >> 6, lane = t & 63;
    int q = 4 * b + wv;
    int c = lane & 15, prt = lane >> 4;
    int dg = deg[q];
    const int* arow = adj + (size_t)q * ADJ_STRIDE;
    float acc = 0.f;
    for (int j = prt; j < dg; j += 4)
        acc += h2s[(size_t)arow[j] * C_ + c];
    acc += __shfl_down(acc, 32);
    acc += __shfl_down(acc, 16);
    if (lane < 16)
        out[(size_t)q * C_ + c] = dinv[q] * acc + bias[c];
}

// ---------------- launch ----------------

extern "C" void kernel_launch(void* const* d_in, const int* in_sizes, int n_in,
                              void* d_out, int out_size, void* d_ws, size_t ws_size,
                              hipStream_t stream) {
    const int*   attr_row = (const int*)d_in[0];
    const int*   attr_col = (const int*)d_in[1];
    const int*   edge     = (const int*)d_in[2];   // [2][E_]
    const int*   jmsk     = (const int*)d_in[3];   // [2][NNZ_JM]
    const int*   jaug     = (const int*)d_in[4];   // [2][NNZ_JA]
    const float* w1       = (const float*)d_in[5]; // [H_][D_]
    const float* w2       = (const float*)d_in[6]; // [C_][H_]
    const float* bias2    = (const float*)d_in[7]; // [C_]
    float*       out      = (float*)d_out;

    char* ws = (char*)d_ws;
    unsigned*      xslot = (unsigned*)(ws + OFF_XSLOT);
    unsigned char* ebb   = (unsigned char*)(ws + OFF_EBB);
    unsigned char* xb    = (unsigned char*)(ws + OFF_XB);
    unsigned*      abt   = (unsigned*)(ws + OFF_ABT);
    unsigned*      cnt   = (unsigned*)(ws + OFF_CNT);
    unsigned*      ccol  = (unsigned*)(ws + OFF_CCOL);
    int*           adj   = (int*)(ws + OFF_ADJ);
    float*         dinv  = (float*)(ws + OFF_DINV);
    int*           deg   = (int*)(ws + OFF_DEG);
    _Float16*      w1t   = (_Float16*)(ws + OFF_W1T);
    _Float16*      h1s   = (_Float16*)(ws + OFF_H1);
    float*         h2s   = (float*)(ws + OFF_H2);

    k_pre<<<ZB_BLOCKS + XS_BLOCKS + TR_BLOCKS, NT, 0, stream>>>(
        w1, w1t, attr_row, attr_col, xslot, (uint4*)(ws + OFF_EBB));
    k_scat<<<SC_TOT, NT, 0, stream>>>(attr_row, attr_col, edge, jaug, xslot,
                                      ebb, xb, abt, cnt, ccol);
    k_probe<<<(NNZ_JM + NT - 1) / NT, NT, 0, stream>>>(jmsk, ebb, abt);
    k_rowh1<<<N_ / 4, NT, 0, stream>>>(abt, xb, cnt, ccol, w1t, dinv, deg, adj, h1s);
    k_prop1<<<N_ / 4, NT, 0, stream>>>(adj, deg, dinv, h1s, w2, h2s);
    k_prop2<<<N_ / 4, NT, 0, stream>>>(adj, deg, dinv, h2s, bias2, out);
}

// Round 12
// 77.501 us; speedup vs baseline: 1.0394x; 1.0394x over previous
//
#include <hip/hip_runtime.h>

#define N_      4096
#define D_      4096
#define H_      256
#define C_      16
#define NNZ_ATTR 262144
#define E_      131072
#define NNZ_JM  400000
#define NNZ_JA  80000
#define WORDS   128        // N_/32 words per bitmask row
#define ADJ_STRIDE 128     // max neighbors kept per row (deg ~21 avg, max ~45)
#define NT      256
#define MAXCOLS 160        // attr cols per row (mean 64, 5-sigma ~104) + dups
#define DUPS    16         // dup slots per row (expected ~0.5/row)

typedef _Float16 half8v __attribute__((ext_vector_type(8)));
typedef _Float16 half2v __attribute__((ext_vector_type(2)));

// ---------------- workspace layout (bytes), ~12.8 MB ----------------
#define OFF_XBIT ((size_t)0)                        // 2 MB  attr bit mask [r][words]
#define OFF_EBT  ((size_t)(2u<<20))                 // 2 MB  edge bitmask transposed [q][p]
#define OFF_ABT  ((size_t)(4u<<20))                 // 2 MB  a_aug^T bitmask [q][p]
#define OFF_DUPC ((size_t)(6u<<20))                 // 16 KB dup counters [N]
#define OFF_DUPL (OFF_DUPC + (size_t)(16u<<10))     // 256 KB dup col slots [N][16]
#define OFF_ADJ  (OFF_DUPL + (size_t)(256u<<10))    // 2 MB  adjacency lists [N][128]
#define OFF_DINV (OFF_ADJ + (size_t)(2u<<20))       // 16 KB
#define OFF_DEG  (OFF_DINV + (size_t)(16u<<10))     // 16 KB
#define OFF_W1T  (OFF_DEG + (size_t)(16u<<10))      // 2 MB  W1^T fp16 [D][H]
#define OFF_H1   (OFF_W1T + (size_t)(2u<<20))       // 2 MB  h1s fp16 [N][H]
#define OFF_H2   (OFF_H1 + (size_t)(2u<<20))        // 256 KB h2s f32

// zero span: xbit+ebt+abt+dupc = 6MB+16KB = 6307840 B = 1540 * 256 * 16 exactly
#define ZB_BLOCKS  1540
#define TR_BLOCKS  1024

// k_scat block ranges
#define SC_ATTR  1024      // attr:  [0,1024)     262144 exact
#define SC_EDGE  1536      // edges: [1024,1536)  131072 exact
#define SC_TOT   1849      // ja:    [1536,1849)  80000 guarded

// ---------------- K1: zero masks + W1 -> W1T fp16 ----------------
__global__ void k_pre(const float* __restrict__ w1, _Float16* __restrict__ w1t,
                      uint4* __restrict__ zbase) {
    __shared__ float tile[32][33];
    int b = blockIdx.x, t = threadIdx.x;
    if (b < ZB_BLOCKS) {
        zbase[(size_t)b * NT + t] = make_uint4(0u, 0u, 0u, 0u);
    } else {
        int bb = b - ZB_BLOCKS;
        int gx = bb & 127, gy = bb >> 7;              // 128 D-tiles, 8 H-tiles
        int tx = t & 31, ty = t >> 5;                 // (32,8)
        int col = gx * 32 + tx;
        #pragma unroll
        for (int j = 0; j < 4; ++j)
            tile[ty + j * 8][tx] = w1[(size_t)(gy * 32 + ty + j * 8) * D_ + col];
        __syncthreads();
        int ocol = gy * 32 + tx;
        #pragma unroll
        for (int j = 0; j < 4; ++j)
            w1t[(size_t)(gx * 32 + ty + j * 8) * H_ + ocol] = (_Float16)tile[tx][ty + j * 8];
    }
}

// ---------------- K2: attr->xbit (dup via returned old) | edges->ebt | ja->abt ----------------
__global__ void k_scat(const int* __restrict__ attr_row, const int* __restrict__ attr_col,
                       const int* __restrict__ edge, const int* __restrict__ jaug,
                       unsigned* __restrict__ xbit, unsigned* __restrict__ ebt,
                       unsigned* __restrict__ abt, unsigned* __restrict__ dupc,
                       unsigned* __restrict__ dupl) {
    const int b = blockIdx.x, t = threadIdx.x;
    if (b < SC_ATTR) {                       // attr: 262144 exact
        int i = b * NT + t;
        int r = attr_row[i], c = attr_col[i];
        unsigned bit = 1u << (c & 31);
        unsigned old = atomicOr(&xbit[(size_t)r * WORDS + (c >> 5)], bit);
        if (old & bit) {                     // duplicate occurrence (~2K total) must accumulate
            unsigned pos = atomicAdd(&dupc[r], 1u);
            if (pos < DUPS) dupl[r * DUPS + pos] = (unsigned)c;
        }
    } else if (b < SC_EDGE) {                // edges -> ebt: 131072 exact
        int j = (b - SC_ATTR) * NT + t;
        int p = edge[j], q = edge[E_ + j];
        atomicOr(&ebt[(size_t)q * WORDS + (p >> 5)], 1u << (p & 31));
    } else {                                 // ja -> abt: 80000 guarded
        int j = (b - SC_EDGE) * NT + t;
        if (j < NNZ_JA) {
            int p = jaug[j], q = jaug[NNZ_JA + j];
            atomicOr(&abt[(size_t)q * WORDS + (p >> 5)], 1u << (p & 31));
        }
    }
}

// ---------------- K3: jm entries probe ebt; hits -> abt (~3K atomics) ----------------
__global__ void k_probe(const int* __restrict__ jmsk,
                        const unsigned* __restrict__ ebt, unsigned* __restrict__ abt) {
    int i = blockIdx.x * NT + threadIdx.x;
    if (i >= NNZ_JM) return;
    int p = jmsk[i], q = jmsk[NNZ_JM + i];
    size_t w = (size_t)q * WORDS + (p >> 5);
    if ((ebt[w] >> (p & 31)) & 1u)
        atomicOr(&abt[w], 1u << (p & 31));
}

// ---------------- K4: abt(+diag) -> adj/dinv/deg; xbit row -> cols; h1s fp16 ----------------
__global__ void k_rowh1(const unsigned* __restrict__ abt, const unsigned* __restrict__ xbit,
                        const unsigned* __restrict__ dupc, const unsigned* __restrict__ dupl,
                        const _Float16* __restrict__ w1t,
                        float* __restrict__ dinv, int* __restrict__ deg,
                        int* __restrict__ adj, _Float16* __restrict__ h1s) {
    __shared__ unsigned cols[MAXCOLS];
    __shared__ int lcnt;
    __shared__ float part[4][2][32][8];   // 8 KB
    __shared__ float sdinv4[4];
    const int b = blockIdx.x, t = threadIdx.x;
    int wv = t >> 6, lane = t & 63;
    int q = 4 * b + wv;
    {   // adjacency extraction, 1 row/wave; diag OR'd in-register (no atomic)
        uint2 m2 = ((const uint2*)(abt + (size_t)q * WORDS))[lane];
        unsigned w0 = m2.x, w1b = m2.y;
        int dw = q >> 5;                      // which 32-bit word holds bit q
        if ((dw >> 1) == lane) {
            if (dw & 1) w1b |= 1u << (q & 31); else w0 |= 1u << (q & 31);
        }
        int c = __popc(w0) + __popc(w1b);
        int pre = c;
        #pragma unroll
        for (int d2 = 1; d2 < 64; d2 <<= 1) {
            int x = __shfl_up(pre, d2);
            if (lane >= d2) pre += x;
        }
        int excl = pre - c;
        int total = __shfl(pre, 63);
        if (lane == 0) {
            float dv = rsqrtf((float)total);
            dinv[q] = dv;
            sdinv4[wv] = dv;
            deg[q] = total < ADJ_STRIDE ? total : ADJ_STRIDE;
        }
        unsigned idx = (unsigned)excl;
        int* arow = adj + (size_t)q * ADJ_STRIDE;
        int base0 = lane * 64;
        while (w0)  { int bp = __ffs(w0) - 1;  w0  &= w0 - 1;  if (idx < ADJ_STRIDE) arow[idx] = base0 + bp;      ++idx; }
        while (w1b) { int bp = __ffs(w1b) - 1; w1b &= w1b - 1; if (idx < ADJ_STRIDE) arow[idx] = base0 + 32 + bp; ++idx; }
    }
    __syncthreads();
    int g = t >> 6, hw = (t >> 5) & 1, l32 = t & 31;
    for (int i = 0; i < 4; ++i) {
        int r = 4 * b + i;
        if (t == 0) lcnt = 0;
        __syncthreads();
        // extract attr cols from the 128-word xbit row (threads 0..127, 1 word each)
        if (t < WORDS) {
            unsigned u = xbit[(size_t)r * WORDS + t];
            while (u) {
                int bp = __ffs(u) - 1; u &= u - 1;
                int idx = atomicAdd(&lcnt, 1);
                if (idx < MAXCOLS) cols[idx] = (unsigned)(t * 32 + bp);
            }
        }
        unsigned dn = dupc[r]; if (dn > (unsigned)DUPS) dn = DUPS;
        if ((unsigned)t < dn) {
            int idx = atomicAdd(&lcnt, 1);
            if (idx < MAXCOLS) cols[idx] = dupl[r * DUPS + t];
        }
        __syncthreads();
        int m = lcnt < MAXCOLS ? lcnt : MAXCOLS;
        float acc[8];
        #pragma unroll
        for (int e = 0; e < 8; ++e) acc[e] = 0.f;
        int sub = (g << 1) + hw;              // 0..7: every-8th col per 32-lane group
        for (int j = 0; j < m; j += 8) {
            int jc = j + sub;
            if (jc < m) {
                unsigned c = cols[jc];
                half8v v = *(const half8v*)(w1t + (size_t)c * H_ + l32 * 8);
                #pragma unroll
                for (int e = 0; e < 8; ++e) acc[e] += (float)v[e];
            }
        }
        #pragma unroll
        for (int e = 0; e < 8; ++e) part[g][hw][l32][e] = acc[e];
        __syncthreads();
        int l = t >> 3, e = t & 7;
        float s = 0.f;
        #pragma unroll
        for (int gg = 0; gg < 4; ++gg) {
            s += part[gg][0][l][e];
            s += part[gg][1][l][e];
        }
        h1s[(size_t)r * H_ + t] = (_Float16)(s * sdinv4[i]);
        __syncthreads();
    }
}

// ---------------- K5: out1 = relu(dinv*sum_adj h1s); h2s = dinv*(out1 @ W2^T) ----------------
__global__ void k_prop1(const int* __restrict__ adj, const int* __restrict__ deg,
                        const float* __restrict__ dinv, const _Float16* __restrict__ h1s,
                        const float* __restrict__ w2, float* __restrict__ h2s) {
    __shared__ int adj_s[128];
    __shared__ float partial2[2][256];
    __shared__ float hrow[256];
    __shared__ float partial[16][17];
    const int b = blockIdx.x, t = threadIdx.x;
    int g2 = t >> 7, tt = t & 127;
    int c = t & 15, gg = t >> 4;
    float w2r[16];
    #pragma unroll
    for (int kk = 0; kk < 16; ++kk) w2r[kk] = w2[(size_t)c * H_ + gg * 16 + kk];
    for (int i = 0; i < 4; ++i) {
        int q = 4 * b + i;
        __syncthreads();
        if (t < ADJ_STRIDE) adj_s[t] = adj[(size_t)q * ADJ_STRIDE + t];
        __syncthreads();
        int dg = deg[q];
        float ax = 0.f, ay = 0.f;
        int j = g2;
        for (; j + 2 < dg; j += 4) {
            int p0 = adj_s[j], p1 = adj_s[j + 2];
            half2v v0 = *(const half2v*)(h1s + (size_t)p0 * H_ + tt * 2);
            half2v v1 = *(const half2v*)(h1s + (size_t)p1 * H_ + tt * 2);
            ax += (float)v0[0] + (float)v1[0];
            ay += (float)v0[1] + (float)v1[1];
        }
        for (; j < dg; j += 2) {
            int p0 = adj_s[j];
            half2v v0 = *(const half2v*)(h1s + (size_t)p0 * H_ + tt * 2);
            ax += (float)v0[0];
            ay += (float)v0[1];
        }
        partial2[g2][2 * tt]     = ax;
        partial2[g2][2 * tt + 1] = ay;
        __syncthreads();
        float dq = dinv[q];
        hrow[t] = fmaxf((partial2[0][t] + partial2[1][t]) * dq, 0.f);
        __syncthreads();
        float p = 0.f;
        #pragma unroll
        for (int kk = 0; kk < 16; ++kk) p += hrow[gg * 16 + kk] * w2r[kk];
        partial[gg][c] = p;
        __syncthreads();
        if (t < 16) {
            float s = 0.f;
            #pragma unroll
            for (int g3 = 0; g3 < 16; ++g3) s += partial[g3][t];
            h2s[(size_t)q * C_ + t] = s * dq;
        }
    }
}

// ---------------- K6: out[q,c] = dinv[q]*sum_adj h2s[p,c] + bias[c] ----------------
__global__ void k_prop2(const int* __restrict__ adj, const int* __restrict__ deg,
                        const float* __restrict__ dinv, const float* __restrict__ h2s,
                        const float* __restrict__ bias, float* __restrict__ out) {
    const int b = blockIdx.x, t = threadIdx.x;
    int wv = t >> 6, lane = t & 63;
    int q = 4 * b + wv;
    int c = lane & 15, prt = lane >> 4;
    int dg = deg[q];
    const int* arow = adj + (size_t)q * ADJ_STRIDE;
    float acc = 0.f;
    for (int j = prt; j < dg; j += 4)
        acc += h2s[(size_t)arow[j] * C_ + c];
    acc += __shfl_down(acc, 32);
    acc += __shfl_down(acc, 16);
    if (lane < 16)
        out[(size_t)q * C_ + c] = dinv[q] * acc + bias[c];
}

// ---------------- launch ----------------

extern "C" void kernel_launch(void* const* d_in, const int* in_sizes, int n_in,
                              void* d_out, int out_size, void* d_ws, size_t ws_size,
                              hipStream_t stream) {
    const int*   attr_row = (const int*)d_in[0];
    const int*   attr_col = (const int*)d_in[1];
    const int*   edge     = (const int*)d_in[2];   // [2][E_]
    const int*   jmsk     = (const int*)d_in[3];   // [2][NNZ_JM]
    const int*   jaug     = (const int*)d_in[4];   // [2][NNZ_JA]
    const float* w1       = (const float*)d_in[5]; // [H_][D_]
    const float* w2       = (const float*)d_in[6]; // [C_][H_]
    const float* bias2    = (const float*)d_in[7]; // [C_]
    float*       out      = (float*)d_out;

    char* ws = (char*)d_ws;
    unsigned*  xbit = (unsigned*)(ws + OFF_XBIT);
    unsigned*  ebt  = (unsigned*)(ws + OFF_EBT);
    unsigned*  abt  = (unsigned*)(ws + OFF_ABT);
    unsigned*  dupc = (unsigned*)(ws + OFF_DUPC);
    unsigned*  dupl = (unsigned*)(ws + OFF_DUPL);
    int*       adj  = (int*)(ws + OFF_ADJ);
    float*     dinv = (float*)(ws + OFF_DINV);
    int*       deg  = (int*)(ws + OFF_DEG);
    _Float16*  w1t  = (_Float16*)(ws + OFF_W1T);
    _Float16*  h1s  = (_Float16*)(ws + OFF_H1);
    float*     h2s  = (float*)(ws + OFF_H2);

    k_pre<<<ZB_BLOCKS + TR_BLOCKS, NT, 0, stream>>>(w1, w1t, (uint4*)d_ws);
    k_scat<<<SC_TOT, NT, 0, stream>>>(attr_row, attr_col, edge, jaug,
                                      xbit, ebt, abt, dupc, dupl);
    k_probe<<<(NNZ_JM + NT - 1) / NT, NT, 0, stream>>>(jmsk, ebt, abt);
    k_rowh1<<<N_ / 4, NT, 0, stream>>>(abt, xbit, dupc, dupl, w1t, dinv, deg, adj, h1s);
    k_prop1<<<N_ / 4, NT, 0, stream>>>(adj, deg, dinv, h1s, w2, h2s);
    k_prop2<<<N_ / 4, NT, 0, stream>>>(adj, deg, dinv, h2s, bias2, out);
}

// Round 13
// 75.082 us; speedup vs baseline: 1.0729x; 1.0322x over previous
//
#include <hip/hip_runtime.h>

#define N_      4096
#define D_      4096
#define H_      256
#define C_      16
#define NNZ_ATTR 262144
#define E_      131072
#define NNZ_JM  400000
#define NNZ_JA  80000
#define WORDS   128        // N_/32 words per bitmask row
#define ADJ_STRIDE 128     // max neighbors kept per row (deg ~21 avg, max ~45)
#define ASTR    128        // attr cols per row cap (mean 64, sd 8; 8-sigma safe)
#define NT      256

typedef _Float16 half8v __attribute__((ext_vector_type(8)));
typedef _Float16 half2v __attribute__((ext_vector_type(2)));

// ---------------- workspace layout (bytes), ~12.8 MB ----------------
#define OFF_EBT  ((size_t)0)                        // 2 MB  edge bitmask transposed [q][p]
#define OFF_ABT  ((size_t)(2u<<20))                 // 2 MB  a_aug^T bitmask [q][p]
#define OFF_CNT  ((size_t)(4u<<20))                 // 256 KB attr counts, 1 per 64B line
#define OFF_DINV (OFF_CNT + (size_t)(256u<<10))     // 16 KB dinv
#define OFF_DEG  (OFF_DINV + (size_t)(16u<<10))     // 16 KB adj degree
#define OFF_CCOL (OFF_DEG + (size_t)(16u<<10))      // 2 MB  attr col slots [N][ASTR]
#define OFF_ADJ  (OFF_CCOL + (size_t)(2u<<20))      // 2 MB  adjacency lists [N][128]
#define OFF_W1T  (OFF_ADJ + (size_t)(2u<<20))       // 2 MB  W1^T fp16 [D][H]
#define OFF_H1   (OFF_W1T + (size_t)(2u<<20))       // 2 MB  h1s fp16 [N][H]
#define OFF_H2   (OFF_H1  + (size_t)(2u<<20))       // 256 KB h2s f32

#define ZERO_BYTES ((size_t)((4u<<20)+(256u<<10)))  // ebt+abt+cnt = 4456448
#define ZB_BLOCKS  1088                             // ZERO_BYTES/16/256 exactly
#define TR_BLOCKS  1024

// k_scat1 block ranges (diag handled in-register in k_rowh1 now)
#define SB_EDGE  1024      // attr: blocks [0,1024)    262144 exact
#define SB_JA    1536      // edge: blocks [1024,1536) 131072 exact
#define SB_TOTAL 1849      // ja:   blocks [1536,1849) 80000 guarded

// ---------------- K1: zero ebt/abt/cnt + W1 -> W1T fp16 ----------------
__global__ void k_pre(const float* __restrict__ w1, _Float16* __restrict__ w1t,
                      uint4* __restrict__ zp) {
    __shared__ float tile[32][33];
    int b = blockIdx.x, t = threadIdx.x;
    if (b < ZB_BLOCKS) {
        zp[(size_t)b * NT + t] = make_uint4(0u, 0u, 0u, 0u);
    } else {
        int bb = b - ZB_BLOCKS;
        int gx = bb & 127, gy = bb >> 7;     // 128 D-tiles, 8 H-tiles
        int tx = t & 31, ty = t >> 5;        // (32,8)
        int col = gx * 32 + tx;
        #pragma unroll
        for (int j = 0; j < 4; ++j)
            tile[ty + j * 8][tx] = w1[(size_t)(gy * 32 + ty + j * 8) * D_ + col];
        __syncthreads();
        int ocol = gy * 32 + tx;
        #pragma unroll
        for (int j = 0; j < 4; ++j)
            w1t[(size_t)(gx * 32 + ty + j * 8) * H_ + ocol] = (_Float16)tile[tx][ty + j * 8];
    }
}

// ---------------- K2: attr scatter | edge bitmask | ja->abt ----------------
__global__ void k_scat1(const int* __restrict__ attr_row, const int* __restrict__ attr_col,
                        const int* __restrict__ edge, const int* __restrict__ jaug,
                        unsigned* __restrict__ ebt, unsigned* __restrict__ abt,
                        unsigned* __restrict__ cnt, unsigned* __restrict__ ccol) {
    const int b = blockIdx.x, t = threadIdx.x;
    if (b < SB_EDGE) {                       // attr: 262144 exact
        int i = b * NT + t;
        int r = attr_row[i];
        unsigned pos = atomicAdd(&cnt[r << 4], 1u);   // padded: 1 counter / 64B line
        if (pos < ASTR) ccol[(size_t)r * ASTR + pos] = (unsigned)attr_col[i];
    } else if (b < SB_JA) {                  // edges -> ebt: 131072 exact
        int j = (b - SB_EDGE) * NT + t;
        int p = edge[j], q = edge[E_ + j];
        atomicOr(&ebt[(size_t)q * WORDS + (p >> 5)], 1u << (p & 31));
    } else {                                 // ja -> abt: 80000 guarded
        int j = (b - SB_JA) * NT + t;
        if (j < NNZ_JA) {
            int p = jaug[j], q = jaug[NNZ_JA + j];
            atomicOr(&abt[(size_t)q * WORDS + (p >> 5)], 1u << (p & 31));
        }
    }
}

// ---------------- K3: jm entries probe ebt; hits -> abt (~3K atomics) ----------------
__global__ void k_scat2(const int* __restrict__ jmsk,
                        const unsigned* __restrict__ ebt, unsigned* __restrict__ abt) {
    int i = blockIdx.x * NT + threadIdx.x;
    if (i >= NNZ_JM) return;
    int p = jmsk[i], q = jmsk[NNZ_JM + i];
    size_t w = (size_t)q * WORDS + (p >> 5);
    if ((ebt[w] >> (p & 31)) & 1u)
        atomicOr(&abt[w], 1u << (p & 31));
}

// ---------------- K4: abt(+in-reg diag) -> adj/dinv/deg, then h1s fp16 ----------------
__global__ void k_rowh1(const unsigned* __restrict__ abt, const unsigned* __restrict__ cnt,
                        const unsigned* __restrict__ ccol, const _Float16* __restrict__ w1t,
                        float* __restrict__ dinv, int* __restrict__ deg,
                        int* __restrict__ adj, _Float16* __restrict__ h1s) {
    __shared__ unsigned cols[ASTR];
    __shared__ float part[4][2][32][8];   // 8 KB
    __shared__ float sdinv4[4];
    const int b = blockIdx.x, t = threadIdx.x;
    int wv = t >> 6, lane = t & 63;
    int q = 4 * b + wv;
    {
        uint2 m2 = ((const uint2*)(abt + (size_t)q * WORDS))[lane];
        unsigned w0 = m2.x, w1b = m2.y;
        int dw = q >> 5;                      // diag: OR bit q in-register (no atomic)
        if ((dw >> 1) == lane) {
            if (dw & 1) w1b |= 1u << (q & 31); else w0 |= 1u << (q & 31);
        }
        int c = __popc(w0) + __popc(w1b);
        int pre = c;
        #pragma unroll
        for (int d2 = 1; d2 < 64; d2 <<= 1) {
            int x = __shfl_up(pre, d2);
            if (lane >= d2) pre += x;
        }
        int excl = pre - c;
        int total = __shfl(pre, 63);
        if (lane == 0) {
            float dv = rsqrtf((float)total);
            dinv[q] = dv;
            sdinv4[wv] = dv;
            deg[q] = total < ADJ_STRIDE ? total : ADJ_STRIDE;
        }
        unsigned idx = (unsigned)excl;
        int* arow = adj + (size_t)q * ADJ_STRIDE;
        int base0 = lane * 64;
        while (w0)  { int bp = __ffs(w0) - 1;  w0  &= w0 - 1;  if (idx < ADJ_STRIDE) arow[idx] = base0 + bp;      ++idx; }
        while (w1b) { int bp = __ffs(w1b) - 1; w1b &= w1b - 1; if (idx < ADJ_STRIDE) arow[idx] = base0 + 32 + bp; ++idx; }
    }
    __syncthreads();
    int g = t >> 6, hw = (t >> 5) & 1, l32 = t & 31;
    for (int i = 0; i < 4; ++i) {
        int r = 4 * b + i;
        int m = (int)min(cnt[r << 4], (unsigned)ASTR);
        if (t < m) cols[t] = ccol[(size_t)r * ASTR + t];
        __syncthreads();
        float acc[8];
        #pragma unroll
        for (int e = 0; e < 8; ++e) acc[e] = 0.f;
        int sub = (g << 1) + hw;             // 0..7: every-8th col per 32-lane group
        for (int j = 0; j < m; j += 8) {
            int jc = j + sub;
            if (jc < m) {
                unsigned c = cols[jc];
                half8v v = *(const half8v*)(w1t + (size_t)c * H_ + l32 * 8);
                #pragma unroll
                for (int e = 0; e < 8; ++e) acc[e] += (float)v[e];
            }
        }
        #pragma unroll
        for (int e = 0; e < 8; ++e) part[g][hw][l32][e] = acc[e];
        __syncthreads();
        int l = t >> 3, e = t & 7;
        float s = 0.f;
        #pragma unroll
        for (int gg = 0; gg < 4; ++gg) {
            s += part[gg][0][l][e];
            s += part[gg][1][l][e];
        }
        h1s[(size_t)r * H_ + t] = (_Float16)(s * sdinv4[i]);
        __syncthreads();
    }
}

// ---------------- K5: out1 = relu(dinv*sum_adj h1s); h2s = dinv*(out1 @ W2^T) ----------------
__global__ void k_prop1(const int* __restrict__ adj, const int* __restrict__ deg,
                        const float* __restrict__ dinv, const _Float16* __restrict__ h1s,
                        const float* __restrict__ w2, float* __restrict__ h2s) {
    __shared__ int adj_s[128];
    __shared__ float partial2[2][256];
    __shared__ float hrow[256];
    __shared__ float partial[16][17];
    const int b = blockIdx.x, t = threadIdx.x;
    int g2 = t >> 7, tt = t & 127;
    int c = t & 15, gg = t >> 4;
    float w2r[16];
    #pragma unroll
    for (int kk = 0; kk < 16; ++kk) w2r[kk] = w2[(size_t)c * H_ + gg * 16 + kk];
    for (int i = 0; i < 4; ++i) {
        int q = 4 * b + i;
        __syncthreads();
        if (t < ADJ_STRIDE) adj_s[t] = adj[(size_t)q * ADJ_STRIDE + t];
        __syncthreads();
        int dg = deg[q];
        float ax = 0.f, ay = 0.f;
        int j = g2;
        for (; j + 2 < dg; j += 4) {
            int p0 = adj_s[j], p1 = adj_s[j + 2];
            half2v v0 = *(const half2v*)(h1s + (size_t)p0 * H_ + tt * 2);
            half2v v1 = *(const half2v*)(h1s + (size_t)p1 * H_ + tt * 2);
            ax += (float)v0[0] + (float)v1[0];
            ay += (float)v0[1] + (float)v1[1];
        }
        for (; j < dg; j += 2) {
            int p0 = adj_s[j];
            half2v v0 = *(const half2v*)(h1s + (size_t)p0 * H_ + tt * 2);
            ax += (float)v0[0];
            ay += (float)v0[1];
        }
        partial2[g2][2 * tt]     = ax;
        partial2[g2][2 * tt + 1] = ay;
        __syncthreads();
        float dq = dinv[q];
        hrow[t] = fmaxf((partial2[0][t] + partial2[1][t]) * dq, 0.f);
        __syncthreads();
        float p = 0.f;
        #pragma unroll
        for (int kk = 0; kk < 16; ++kk) p += hrow[gg * 16 + kk] * w2r[kk];
        partial[gg][c] = p;
        __syncthreads();
        if (t < 16) {
            float s = 0.f;
            #pragma unroll
            for (int g3 = 0; g3 < 16; ++g3) s += partial[g3][t];
            h2s[(size_t)q * C_ + t] = s * dq;
        }
    }
}

// ---------------- K6: out[q,c] = dinv[q]*sum_adj h2s[p,c] + bias[c] ----------------
__global__ void k_prop2(const int* __restrict__ adj, const int* __restrict__ deg,
                        const float* __restrict__ dinv, const float* __restrict__ h2s,
                        const float* __restrict__ bias, float* __restrict__ out) {
    const int b = blockIdx.x, t = threadIdx.x;
    int wv = t >> 6, lane = t & 63;
    int q = 4 * b + wv;
    int c = lane & 15, prt = lane >> 4;
    int dg = deg[q];
    const int* arow = adj + (size_t)q * ADJ_STRIDE;
    float acc = 0.f;
    for (int j = prt; j < dg; j += 4)
        acc += h2s[(size_t)arow[j] * C_ + c];
    acc += __shfl_down(acc, 32);
    acc += __shfl_down(acc, 16);
    if (lane < 16)
        out[(size_t)q * C_ + c] = dinv[q] * acc + bias[c];
}

// ---------------- launch ----------------

extern "C" void kernel_launch(void* const* d_in, const int* in_sizes, int n_in,
                              void* d_out, int out_size, void* d_ws, size_t ws_size,
                              hipStream_t stream) {
    const int*   attr_row = (const int*)d_in[0];
    const int*   attr_col = (const int*)d_in[1];
    const int*   edge     = (const int*)d_in[2];   // [2][E_]
    const int*   jmsk     = (const int*)d_in[3];   // [2][NNZ_JM]
    const int*   jaug     = (const int*)d_in[4];   // [2][NNZ_JA]
    const float* w1       = (const float*)d_in[5]; // [H_][D_]
    const float* w2       = (const float*)d_in[6]; // [C_][H_]
    const float* bias2    = (const float*)d_in[7]; // [C_]
    float*       out      = (float*)d_out;

    char* ws = (char*)d_ws;
    unsigned*  ebt  = (unsigned*)(ws + OFF_EBT);
    unsigned*  abt  = (unsigned*)(ws + OFF_ABT);
    unsigned*  cnt  = (unsigned*)(ws + OFF_CNT);
    float*     dinv = (float*)(ws + OFF_DINV);
    int*       deg  = (int*)(ws + OFF_DEG);
    unsigned*  ccol = (unsigned*)(ws + OFF_CCOL);
    int*       adj  = (int*)(ws + OFF_ADJ);
    _Float16*  w1t  = (_Float16*)(ws + OFF_W1T);
    _Float16*  h1s  = (_Float16*)(ws + OFF_H1);
    float*     h2s  = (float*)(ws + OFF_H2);

    k_pre<<<ZB_BLOCKS + TR_BLOCKS, NT, 0, stream>>>(w1, w1t, (uint4*)d_ws);
    k_scat1<<<SB_TOTAL, NT, 0, stream>>>(attr_row, attr_col, edge, jaug,
                                         ebt, abt, cnt, ccol);
    k_scat2<<<(NNZ_JM + NT - 1) / NT, NT, 0, stream>>>(jmsk, ebt, abt);
    k_rowh1<<<N_ / 4, NT, 0, stream>>>(abt, cnt, ccol, w1t, dinv, deg, adj, h1s);
    k_prop1<<<N_ / 4, NT, 0, stream>>>(adj, deg, dinv, h1s, w2, h2s);
    k_prop2<<<N_ / 4, NT, 0, stream>>>(adj, deg, dinv, h2s, bias2, out);
}